// Round 1
// 1020.119 us; speedup vs baseline: 1.0290x; 1.0290x over previous
//
#include <hip/hip_runtime.h>
#include <math.h>

// GNN: 3x (SAGEConv -> TopKPool -> readout) + MLP head.
//  - msg = relu(lin(x_src)) depends only on src => per-NODE linear.
//  - GEMMs on matrix cores via fp16x2 split (C = Ahi*Whi + Ahi*Wlo + Alo*Whi).
//  - msg output Y kept in f16 ONLY: f16 is monotone so max(f16) = f16(max) --
//    aggregation is exact in f16; only the aggregate's lo (~2^-12 rel) is
//    dropped entering the update GEMM. Halves aggr gather bytes; per-graph
//    slice 3.2MB fits the 4MB per-XCD L2 (r7: fp32 slice missed, FETCH=2x).
//  - update GEMM A0 (=G) has lo==0 -> its Alo*Whi segment covers only the
//    x-half of K: 20 MFMA chunks instead of 24.
//  - CSR built once (layer 1, XCD-swizzled); layers 2/3 reuse via cur/org.
//  - top-k: LDS-resident mono32 keys, radix select + exact tie-break.
//  - readout into per-layer zmax/zsum slots; MLP decodes.
//  - r8: hmax8 via __builtin_elementwise_max -> 4x v_pk_max_f16 instead of
//    per-element cmp+cndmask+repack (~30-45 VALU). aggr_max was VALU-bound
//    (VALUBusy 80%, HBM 8%); this cuts its dynamic instr count ~3-4x.

typedef unsigned int uint;
typedef unsigned long long ull;

typedef _Float16 h8v __attribute__((ext_vector_type(8)));
typedef _Float16 h4v __attribute__((ext_vector_type(4)));
typedef _Float16 h2v __attribute__((ext_vector_type(2)));
typedef float v4f __attribute__((ext_vector_type(4)));

struct hl16 { _Float16 hi, lo; };

__device__ __forceinline__ float4 ld4(const float* p) { return *reinterpret_cast<const float4*>(p); }
__device__ __forceinline__ float2 ld2(const float* p) { return *reinterpret_cast<const float2*>(p); }

__device__ __forceinline__ uint mono32(float f) {
    uint b = __float_as_uint(f);
    return b ^ ((uint)((int)b >> 31) | 0x80000000u);
}

__device__ __forceinline__ hl16 split16(float x) {
    hl16 r;
    r.hi = (_Float16)x;
    r.lo = (_Float16)(x - (float)r.hi);
    return r;
}

__device__ __forceinline__ h8v hmax8(h8v a, h8v b) {
    // maxnum -> v_pk_max_f16 x4. Inputs are relu outputs (no NaN), so this is
    // exactly equivalent to the element-wise (a>b)?a:b it replaces.
    return __builtin_elementwise_max(a, b);
}

// ---------------- MFMA GEMM (fp16x2 split) ----------------
// A0Z: A0's lo is identically zero (seg-2 covers only k in [128,K)).
// OUT16: store output as f16 (else fp32).
template<int K, bool A0Z, bool OUT16>
__global__ __launch_bounds__(256, 2)
void mfma_gemm(const _Float16* __restrict__ A0hi, const _Float16* __restrict__ A0lo,
               const _Float16* __restrict__ A1hi, const _Float16* __restrict__ A1lo,
               const _Float16* __restrict__ Whi, const _Float16* __restrict__ Wlo,
               const float* __restrict__ bias, void* __restrict__ outv, int M)
{
    constexpr int LDT = 40;                     // padded k-stride (f16)
    __shared__ __align__(16) _Float16 As[128 * LDT];
    __shared__ __align__(16) _Float16 Ws[128 * LDT];
    const int tid = threadIdx.x;
    const int lane = tid & 63;
    const int wv = tid >> 6;
    const int wr = (wv >> 1) * 64;              // wave row base
    const int wc = (wv & 1) * 64;               // wave col base
    const int quad = lane >> 4;
    const int l16 = lane & 15;
    const int row0 = blockIdx.x * 128;

    const int sr0 = tid >> 2;                   // 0..63
    const int sr1 = sr0 + 64;                   // 64..127
    const int sq = (tid & 3) * 8;               // k offset in chunk
    const bool ok0 = (row0 + sr0) < M;
    const bool ok1 = (row0 + sr1) < M;

    v4f acc[4][4];
#pragma unroll
    for (int i = 0; i < 4; ++i)
#pragma unroll
        for (int j = 0; j < 4; ++j) acc[i][j] = (v4f){0.f, 0.f, 0.f, 0.f};

    constexpr int CPS = K / 32;
    constexpr int NS2 = A0Z ? (K - 128) / 32 : CPS;   // seg-2 chunk count
    constexpr int NC = 2 * CPS + NS2;
    float4 pa0, pa1, pw0, pw1;
    const float4 f4z = make_float4(0.f, 0.f, 0.f, 0.f);

#define GLOAD(C) do { \
        int kc_, kk_; const _Float16 *Wp_, *Ap_; bool lo_ = (C) >= 2 * CPS; \
        if ((C) < CPS)          { kc_ = (C) * 32;          Wp_ = Whi; } \
        else if ((C) < 2 * CPS) { kc_ = ((C) - CPS) * 32;  Wp_ = Wlo; } \
        else                    { kc_ = ((C) - 2 * CPS) * 32 + (A0Z ? 128 : 0); Wp_ = Whi; } \
        if (K == 256 && kc_ >= 128) { Ap_ = lo_ ? A1lo : A1hi; kk_ = kc_ - 128; } \
        else                        { Ap_ = lo_ ? A0lo : A0hi; kk_ = kc_; } \
        pa0 = ok0 ? ld4((const float*)(Ap_ + (size_t)(row0 + sr0) * 128 + kk_ + sq)) : f4z; \
        pa1 = ok1 ? ld4((const float*)(Ap_ + (size_t)(row0 + sr1) * 128 + kk_ + sq)) : f4z; \
        pw0 = ld4((const float*)(Wp_ + (size_t)sr0 * K + kc_ + sq)); \
        pw1 = ld4((const float*)(Wp_ + (size_t)sr1 * K + kc_ + sq)); \
    } while (0)

#define SSTORE() do { \
        *reinterpret_cast<float4*>(&As[sr0 * LDT + sq]) = pa0; \
        *reinterpret_cast<float4*>(&As[sr1 * LDT + sq]) = pa1; \
        *reinterpret_cast<float4*>(&Ws[sr0 * LDT + sq]) = pw0; \
        *reinterpret_cast<float4*>(&Ws[sr1 * LDT + sq]) = pw1; \
    } while (0)

    GLOAD(0);
#pragma unroll
    for (int c = 0; c < NC; ++c) {
        SSTORE();
        __syncthreads();
        if (c + 1 < NC) GLOAD(c + 1);
        h8v af[4], bf[4];
#pragma unroll
        for (int rt = 0; rt < 4; ++rt)
            af[rt] = *reinterpret_cast<const h8v*>(&As[(wr + rt * 16 + l16) * LDT + quad * 8]);
#pragma unroll
        for (int ct = 0; ct < 4; ++ct)
            bf[ct] = *reinterpret_cast<const h8v*>(&Ws[(wc + ct * 16 + l16) * LDT + quad * 8]);
#pragma unroll
        for (int rt = 0; rt < 4; ++rt)
#pragma unroll
            for (int ct = 0; ct < 4; ++ct)
                acc[rt][ct] = __builtin_amdgcn_mfma_f32_16x16x32_f16(
                    af[rt], bf[ct], acc[rt][ct], 0, 0, 0);
        if (c + 1 < NC) __syncthreads();
    }
#undef GLOAD
#undef SSTORE

    float bv[4];
#pragma unroll
    for (int ct = 0; ct < 4; ++ct)
        bv[ct] = bias ? bias[wc + ct * 16 + l16] : 0.f;
#pragma unroll
    for (int rt = 0; rt < 4; ++rt) {
        int rb = row0 + wr + rt * 16 + quad * 4;
#pragma unroll
        for (int r = 0; r < 4; ++r) {
            int row = rb + r;
            if (row < M) {
                if (OUT16) {
                    _Float16* op = (_Float16*)outv + (size_t)row * 128;
#pragma unroll
                    for (int ct = 0; ct < 4; ++ct)
                        op[wc + ct * 16 + l16] =
                            (_Float16)fmaxf(acc[rt][ct][r] + bv[ct], 0.f);
                } else {
                    float* op = (float*)outv + (size_t)row * 128;
#pragma unroll
                    for (int ct = 0; ct < 4; ++ct)
                        op[wc + ct * 16 + l16] = fmaxf(acc[rt][ct][r] + bv[ct], 0.f);
                }
            }
        }
    }
}

// ---------------- prep: weight + x0 fp16x2 conversion ----------------
__global__ void prep_weights(const float* __restrict__ s0, const float* __restrict__ s1,
                             const float* __restrict__ s2, const float* __restrict__ s3,
                             const float* __restrict__ s4, const float* __restrict__ s5,
                             _Float16* __restrict__ WLhi, _Float16* __restrict__ WLlo,
                             _Float16* __restrict__ WUhi, _Float16* __restrict__ WUlo)
{
    int i = blockIdx.x * 256 + threadIdx.x;
    if (i < 3 * 16384) {
        int m = i / 16384, o = i - m * 16384;
        const float* s = (m == 0) ? s0 : (m == 1) ? s2 : s4;
        hl16 r = split16(s[o]);
        WLhi[i] = r.hi; WLlo[i] = r.lo;
    } else if (i < 3 * 16384 + 3 * 32768) {
        int j = i - 3 * 16384;
        int m = j / 32768, o = j - m * 32768;
        const float* s = (m == 0) ? s1 : (m == 1) ? s3 : s5;
        hl16 r = split16(s[o]);
        WUhi[j] = r.hi; WUlo[j] = r.lo;
    }
}

__global__ void convert_x(const float* __restrict__ x, _Float16* __restrict__ hi,
                          _Float16* __restrict__ lo, int total4)
{
    int i = blockIdx.x * 256 + threadIdx.x;
    if (i >= total4) return;
    float4 v = ld4(x + (size_t)i * 4);
    h4v H, L;
    hl16 r0 = split16(v.x); H[0] = r0.hi; L[0] = r0.lo;
    hl16 r1 = split16(v.y); H[1] = r1.hi; L[1] = r1.lo;
    hl16 r2 = split16(v.z); H[2] = r2.hi; L[2] = r2.lo;
    hl16 r3 = split16(v.w); H[3] = r3.hi; L[3] = r3.lo;
    *reinterpret_cast<h4v*>(hi + (size_t)i * 4) = H;
    *reinterpret_cast<h4v*>(lo + (size_t)i * 4) = L;
}

// ---------------- CSR build (layer 1 only, XCD-swizzled by graph) ----------------
__global__ void edge_hist(const int* __restrict__ edst, int* __restrict__ deg, int Eg)
{
    int g = blockIdx.x & 7;
    int c = blockIdx.x >> 3;
    int o = c * 256 + threadIdx.x;
    if (o >= Eg) return;
    atomicAdd(&deg[edst[g * Eg + o]], 1);
}

__global__ __launch_bounds__(1024)
void scan_single(const int* __restrict__ deg, int* __restrict__ rowptr, int M)
{
    __shared__ int wsum[16];
    __shared__ int carry_s;
    int t = threadIdx.x;
    int lane = t & 63;
    int wv = t >> 6;
    int carry = 0;
    for (int base = 0; base < M; base += 4096) {
        int i = base + t * 4;
        int4 v = make_int4(0, 0, 0, 0);
        if (i + 3 < M) v = *reinterpret_cast<const int4*>(deg + i);
        else {
            if (i     < M) v.x = deg[i];
            if (i + 1 < M) v.y = deg[i + 1];
            if (i + 2 < M) v.z = deg[i + 2];
        }
        int tsum = v.x + v.y + v.z + v.w;
        int sc = tsum;
#pragma unroll
        for (int off = 1; off < 64; off <<= 1) {
            int x = __shfl_up(sc, off);
            if (lane >= off) sc += x;
        }
        if (lane == 63) wsum[wv] = sc;
        __syncthreads();
        if (wv == 0 && lane < 16) {
            int ws = wsum[lane];
            int s2 = ws;
#pragma unroll
            for (int off = 1; off < 16; off <<= 1) {
                int x = __shfl_up(s2, off);
                if (lane >= off) s2 += x;
            }
            wsum[lane] = s2 - ws;
            if (lane == 15) carry_s = s2;
        }
        __syncthreads();
        int run = carry + wsum[wv] + sc - tsum;
        if (i     < M) rowptr[i]     = run; run += v.x;
        if (i + 1 < M) rowptr[i + 1] = run; run += v.y;
        if (i + 2 < M) rowptr[i + 2] = run; run += v.z;
        if (i + 3 < M) rowptr[i + 3] = run;
        carry += carry_s;
        __syncthreads();
    }
}

// uses rowptr as cursor: afterwards rowptr[v] == end(v), beg(v) = rowptr[v-1]
__global__ void edge_place(const int* __restrict__ esrc, const int* __restrict__ edst,
                           int* __restrict__ rowptr, int* __restrict__ csr, int Eg)
{
    int g = blockIdx.x & 7;
    int c = blockIdx.x >> 3;
    int o = c * 256 + threadIdx.x;
    if (o >= Eg) return;
    int i = g * Eg + o;
    int pos = atomicAdd(&rowptr[edst[i]], 1);
    csr[pos] = esrc[i];
}

// compose pooling maps after each pool
__global__ void compose_kernel(int* __restrict__ cur, const int* __restrict__ newpos,
                               const int* __restrict__ oldidx, const int* __restrict__ org_in,
                               int* __restrict__ org_out, int N, int Mnew, int Mout, int first)
{
    int i = blockIdx.x * 256 + threadIdx.x;
    if (i < N) {
        int c = first ? i : cur[i];
        int r = -1;
        if (c >= 0) {
            int np = newpos[c];
            if (np < Mout) r = np;
        }
        cur[i] = r;
    }
    if (i < Mnew)
        org_out[i] = first ? oldidx[i] : org_in[oldidx[i]];
}

// aggr[u] = f16-exact max(Yh[u], Yh[src..]) over layer-1 in-edges of org[u],
// src mapped via cur. grid = M/2: blockIdx&1 = feature half, 4 nodes/block,
// 8 edges/wave-instruction (8 lanes x h8v), XCD swizzle by graph.
__global__ __launch_bounds__(256)
void aggr_max(const _Float16* __restrict__ Yh, const int* __restrict__ rowptr,
              const int* __restrict__ csr, const int* __restrict__ cur,
              const int* __restrict__ org, _Float16* __restrict__ Ghi, int k)
{
    int b = blockIdx.x;
    int half = b & 1;
    int bb = b >> 1;
    int g = bb & 7;
    int chunk = bb >> 3;
    int wid = __builtin_amdgcn_readfirstlane((int)(threadIdx.x >> 6));
    int lane = threadIdx.x & 63;
    int node = g * k + chunk * 4 + wid;
    int sub = lane >> 3;                       // edge slot 0..7
    int fo = (lane & 7) * 8 + half * 64;       // feature offset (8 f16)
    int v0 = org ? org[node] : node;
    int end = rowptr[v0];
    int beg = v0 ? rowptr[v0 - 1] : 0;
    h8v acc = *reinterpret_cast<const h8v*>(Yh + (size_t)node * 128 + fo);
    int p = beg;
    for (; p + 8 <= end; p += 8) {
        int s = csr[p + sub];
        if (cur) { int c2 = cur[s]; s = (c2 >= 0) ? c2 : node; }
        h8v v = *reinterpret_cast<const h8v*>(Yh + (size_t)s * 128 + fo);
        acc = hmax8(acc, v);
    }
    if (p < end) {
        int idx = p + sub;
        int s = node;
        if (idx < end) {
            s = csr[idx];
            if (cur) { int c2 = cur[s]; s = (c2 >= 0) ? c2 : node; }
        }
        h8v v = *reinterpret_cast<const h8v*>(Yh + (size_t)s * 128 + fo);
        acc = hmax8(acc, v);
    }
#pragma unroll
    for (int off = 8; off <= 32; off <<= 1) {
        int4 u = *reinterpret_cast<int4*>(&acc);
        int4 o;
        o.x = __shfl_xor(u.x, off);
        o.y = __shfl_xor(u.y, off);
        o.z = __shfl_xor(u.z, off);
        o.w = __shfl_xor(u.w, off);
        acc = hmax8(acc, *reinterpret_cast<h8v*>(&o));
    }
    if (sub == 0)
        *reinterpret_cast<h8v*>(Ghi + (size_t)node * 128 + fo) = acc;
}

__global__ __launch_bounds__(256)
void score_kernel(const float* __restrict__ H, const float* __restrict__ wp,
                  float* __restrict__ s, int M)
{
    int wid = threadIdx.x >> 6;
    int lane = threadIdx.x & 63;
    int node = blockIdx.x * 4 + wid;
    if (node >= M) return;
    float2 h = ld2(H + (size_t)node * 128 + lane * 2);
    float2 w = ld2(wp + lane * 2);
    float d = h.x * w.x + h.y * w.y;
    float nn = w.x * w.x + w.y * w.y;
    for (int off = 1; off < 64; off <<= 1) {
        d += __shfl_xor(d, off);
        nn += __shfl_xor(nn, off);
    }
    if (lane == 0) s[node] = d / sqrtf(nn);
}

// Per-graph exact top-k: LDS-resident mono32 keys, 4-pass radix select +
// exact lowest-index tie-break (jax.lax.top_k order).
__global__ __launch_bounds__(1024)
void topk_kernel(const float* __restrict__ s, int* __restrict__ newpos,
                 int* __restrict__ oldidx, int n, int k, int Mout)
{
    __shared__ uint keys[12512];
    __shared__ int hist[256];
    __shared__ uint sh_prefix;
    __shared__ int sh_need;
    __shared__ int sh_cnt;
    __shared__ int sh_eq;
    __shared__ int eqlist[2048];
    int g = blockIdx.x;
    int t = threadIdx.x;
    const float* sg = s + (size_t)g * n;
    for (int i = t; i < n; i += 1024) keys[i] = mono32(sg[i]);
    if (t == 0) { sh_prefix = 0u; sh_need = k; sh_cnt = 0; sh_eq = 0; }
    __syncthreads();
    for (int pass = 3; pass >= 0; --pass) {
        int shift = pass * 8;
        if (t < 256) hist[t] = 0;
        __syncthreads();
        uint pref = sh_prefix;
        uint maskhi = (pass == 3) ? 0u : (0xFFFFFFFFu << (shift + 8));
        for (int i = t; i < n; i += 1024) {
            uint m = keys[i];
            if ((m & maskhi) == pref)
                atomicAdd(&hist[(m >> shift) & 255], 1);
        }
        __syncthreads();
        if (t == 0) {
            int need = sh_need;
            int cum = 0, b = 255;
            for (; b > 0; --b) {
                if (cum + hist[b] >= need) break;
                cum += hist[b];
            }
            sh_prefix = pref | ((uint)b << shift);
            sh_need = need - cum;
        }
        __syncthreads();
    }
    uint pivot = sh_prefix;
    int take_eq = sh_need;
    for (int i = t; i < n; i += 1024) {
        uint m = keys[i];
        if (m > pivot) {
            int pos = g * k + atomicAdd(&sh_cnt, 1);
            newpos[g * n + i] = pos;
            oldidx[pos] = g * n + i;
        } else {
            if (m == pivot) {
                int e = atomicAdd(&sh_eq, 1);
                if (e < 2048) eqlist[e] = i;
            }
            newpos[g * n + i] = Mout;
        }
    }
    __syncthreads();
    int ec = sh_eq < 2048 ? sh_eq : 2048;
    for (int e = t; e < ec; e += 1024) {
        int idx = eqlist[e];
        int rank = 0;
        for (int j = 0; j < ec; ++j) rank += (eqlist[j] < idx);
        if (rank < take_eq) {
            int pos = g * k + atomicAdd(&sh_cnt, 1);
            newpos[g * n + idx] = pos;
            oldidx[pos] = g * n + idx;
        }
    }
}

// gather + tanh-gate; writes next layer's f16 splits directly
__global__ __launch_bounds__(256)
void permute_kernel(const float* __restrict__ H, const float* __restrict__ s,
                    const int* __restrict__ oldidx, _Float16* __restrict__ Xhi,
                    _Float16* __restrict__ Xlo, int Mout)
{
    int wid = __builtin_amdgcn_readfirstlane((int)(threadIdx.x >> 6));
    int lane = threadIdx.x & 63;
    int pos = blockIdx.x * 4 + wid;
    if (pos >= Mout) return;
    int old = oldidx[pos];
    float scv = tanhf(s[old]);
    float2 v = ld2(H + (size_t)old * 128 + lane * 2);
    v.x *= scv; v.y *= scv;
    h2v H2, L2;
    hl16 r0 = split16(v.x); H2[0] = r0.hi; L2[0] = r0.lo;
    hl16 r1 = split16(v.y); H2[1] = r1.hi; L2[1] = r1.lo;
    *reinterpret_cast<h2v*>(Xhi + (size_t)pos * 128 + lane * 2) = H2;
    *reinterpret_cast<h2v*>(Xlo + (size_t)pos * 128 + lane * 2) = L2;
}

__global__ __launch_bounds__(128)
void readout_kernel(const _Float16* __restrict__ Xhi, const _Float16* __restrict__ Xlo,
                    uint* __restrict__ zmax, float* __restrict__ zsum, int k, int chunk)
{
    int g = blockIdx.x >> 6;    // 64 chunks per graph
    int c = blockIdx.x & 63;
    int f = threadIdx.x;
    int r0 = c * chunk;
    int r1 = r0 + chunk; if (r1 > k) r1 = k;
    float mx = -INFINITY, sm = 0.f;
    for (int r = r0; r < r1; ++r) {
        size_t idx = (size_t)(g * k + r) * 128 + f;
        float v = (float)Xhi[idx] + (float)Xlo[idx];
        mx = fmaxf(mx, v);
        sm += v;
    }
    atomicMax(&zmax[g * 128 + f], mono32(mx));
    atomicAdd(&zsum[g * 128 + f], sm);
}

__global__ __launch_bounds__(256)
void mlp_kernel(const uint* __restrict__ zmaxu, const float* __restrict__ zsum,
                int k1, int k2, int k3,
                const float* __restrict__ Wl1, const float* __restrict__ bl1,
                const float* __restrict__ Wl2, const float* __restrict__ bl2,
                const float* __restrict__ Wl3, const float* __restrict__ bl3,
                float* __restrict__ out)
{
    __shared__ float zs[8 * 256];
    __shared__ float h1[8 * 128];
    __shared__ float h2[8 * 64];
    int t = threadIdx.x;
    float kk[3] = {(float)k1, (float)k2, (float)k3};
    for (int i = t; i < 2048; i += 256) {
        int g = i >> 8, f = i & 255;
        float a = 0.f;
        if (f < 128) {
            for (int l = 0; l < 3; ++l) {
                uint u = zmaxu[l * 1024 + g * 128 + f];
                a += (u & 0x80000000u) ? __uint_as_float(u ^ 0x80000000u)
                                       : __uint_as_float(~u);
            }
        } else {
            int ff = f - 128;
            for (int l = 0; l < 3; ++l)
                a += zsum[l * 1024 + g * 128 + ff] / kk[l];
        }
        zs[g * 256 + f] = a;
    }
    __syncthreads();
    for (int o = t; o < 1024; o += 256) {
        int g = o >> 7, f = o & 127;
        const float* w = Wl1 + f * 256;
        const float* zz = zs + g * 256;
        float a = 0.f;
        for (int j = 0; j < 256; ++j) a = fmaf(zz[j], w[j], a);
        h1[o] = fmaxf(a + bl1[f], 0.f);
    }
    __syncthreads();
    for (int o = t; o < 512; o += 256) {
        int g = o >> 6, f = o & 63;
        const float* w = Wl2 + f * 128;
        const float* hh = h1 + g * 128;
        float a = 0.f;
        for (int j = 0; j < 128; ++j) a = fmaf(hh[j], w[j], a);
        h2[o] = fmaxf(a + bl2[f], 0.f);
    }
    __syncthreads();
    if (t < 8) {
        const float* hh = h2 + t * 64;
        float a = 0.f;
        for (int j = 0; j < 64; ++j) a = fmaf(hh[j], Wl3[j], a);
        a += bl3[0];
        out[t] = 1.f / (1.f + expf(-a));
    }
}

extern "C" void kernel_launch(void* const* d_in, const int* in_sizes, int n_in,
                              void* d_out, int out_size, void* d_ws, size_t ws_size,
                              hipStream_t stream)
{
    const float* x0 = (const float*)d_in[0];
    const int* e0 = (const int*)d_in[1];
    const int E = in_sizes[1] / 2;
    const int N = in_sizes[0] / 128;
    const int B = 8;
    const int Eg = E / B;

    char* p = (char*)d_ws;
    auto carve = [&](size_t bytes) -> char* {
        char* r = p;
        p += (bytes + 255) & ~(size_t)255;
        return r;
    };
    // ping-pong split buffers; G (aggr out, hi only) aliases the layer's OUTPUT hi
    _Float16* B0h = (_Float16*)carve((size_t)100000 * 128 * 2);
    _Float16* B0l = (_Float16*)carve((size_t)100000 * 128 * 2);
    _Float16* B1h = (_Float16*)carve((size_t)100000 * 128 * 2);
    _Float16* B1l = (_Float16*)carve((size_t)100000 * 128 * 2);
    _Float16* Yh  = (_Float16*)carve((size_t)100000 * 128 * 2);  // msg (f16)
    float* Y      = (float*)carve((size_t)100000 * 128 * 4);     // h (fp32)
    int*   csr    = (int*)carve((size_t)E * 4);
    int*   deg    = (int*)carve(100000 * 4);
    int*   rowptr = (int*)carve(100000 * 4);
    float* sc     = (float*)carve(100000 * 4);
    int*   newpos = (int*)carve(100000 * 4);
    int*   oldidx = (int*)carve(80000 * 4);
    int*   cur    = (int*)carve(100000 * 4);
    int*   orgA   = (int*)carve(80000 * 4);
    int*   orgB   = (int*)carve(80000 * 4);
    _Float16* WLhi = (_Float16*)carve(3 * 16384 * 2);
    _Float16* WLlo = (_Float16*)carve(3 * 16384 * 2);
    _Float16* WUhi = (_Float16*)carve(3 * 32768 * 2);
    _Float16* WUlo = (_Float16*)carve(3 * 32768 * 2);
    uint*  zmaxu  = (uint*)carve(3 * 1024 * 4);   // adjacent to zsum
    float* zsum   = (float*)carve(3 * 1024 * 4);

    (void)hipMemsetAsync(zmaxu, 0, 6 * 1024 * 4, stream);   // zmaxu + zsum
    (void)hipMemsetAsync(deg, 0, (size_t)N * 4, stream);
    prep_weights<<<(3 * 16384 + 3 * 32768 + 255) / 256, 256, 0, stream>>>(
        (const float*)d_in[2], (const float*)d_in[4], (const float*)d_in[6],
        (const float*)d_in[8], (const float*)d_in[10], (const float*)d_in[12],
        WLhi, WLlo, WUhi, WUlo);
    convert_x<<<(N * 32 + 255) / 256, 256, 0, stream>>>(x0, B0h, B0l, N * 32);

    // layer-1 CSR (built once; layers 2/3 reuse via cur/org maps)
    int ebg = 8 * ((Eg + 255) / 256);
    edge_hist<<<ebg, 256, 0, stream>>>(e0 + E, deg, Eg);
    scan_single<<<1, 1024, 0, stream>>>(deg, rowptr, N);
    edge_place<<<ebg, 256, 0, stream>>>(e0, e0 + E, rowptr, csr, Eg);

    int M = N;
    for (int l = 0; l < 3; ++l) {
        int n = M / B;
        int k = (int)ceil(0.8 * (double)n);
        int Mout = B * k;
        const float* blin = (const float*)d_in[3 + 4 * l];
        const float* wp   = (const float*)d_in[5 + 4 * l];
        _Float16* XIh = (l & 1) ? B1h : B0h;
        _Float16* XIl = (l & 1) ? B1l : B0l;
        _Float16* XOh = (l & 1) ? B0h : B1h;
        _Float16* XOl = (l & 1) ? B0l : B1l;
        const int* curp = (l == 0) ? nullptr : cur;
        const int* orgp = (l == 0) ? nullptr : ((l == 1) ? orgA : orgB);
        int gb = (M + 127) / 128;

        // conv: msg linear -> Yh (f16), aggr -> G=XOh (f16, lo==0), update -> Y (fp32)
        mfma_gemm<128, false, true><<<gb, 256, 0, stream>>>(XIh, XIl, nullptr, nullptr,
            WLhi + l * 16384, WLlo + l * 16384, blin, Yh, M);
        aggr_max<<<M / 2, 256, 0, stream>>>(Yh, rowptr, csr, curp, orgp, XOh, n);
        mfma_gemm<256, true, false><<<gb, 256, 0, stream>>>(XOh, nullptr, XIh, XIl,
            WUhi + l * 32768, WUlo + l * 32768, nullptr, Y, M);

        // pool
        score_kernel<<<(M + 3) / 4, 256, 0, stream>>>(Y, wp, sc, M);
        topk_kernel<<<B, 1024, 0, stream>>>(sc, newpos, oldidx, n, k, Mout);
        permute_kernel<<<(Mout + 3) / 4, 256, 0, stream>>>(Y, sc, oldidx, XOh, XOl, Mout);

        // readout into per-layer slots (decoded by mlp_kernel)
        int chunk = (k + 63) / 64;
        readout_kernel<<<B * 64, 128, 0, stream>>>(XOh, XOl,
            zmaxu + l * 1024, zsum + l * 1024, k, chunk);

        if (l < 2) {
            compose_kernel<<<(N + 255) / 256, 256, 0, stream>>>(
                cur, newpos, oldidx, (l == 0) ? nullptr : orgA,
                (l == 0) ? orgA : orgB, N, Mout, Mout, (l == 0) ? 1 : 0);
        }
        M = Mout;
    }

    int kk1 = 10000, kk2 = 8000, kk3 = 6400;
    mlp_kernel<<<1, 256, 0, stream>>>(zmaxu, zsum, kk1, kk2, kk3,
        (const float*)d_in[14], (const float*)d_in[15],
        (const float*)d_in[16], (const float*)d_in[17],
        (const float*)d_in[18], (const float*)d_in[19],
        (float*)d_out);
}